// Round 7
// baseline (96.805 us; speedup 1.0000x reference)
//
#include <hip/hip_runtime.h>

#define BD 64
#define SD 512
#define DD 1024
#define HD 1024
#define TD 9
#define NSEG 16
#define SEGL 32
#define NEGI -1e30f

__device__ __forceinline__ float lse9(const float v[9]) {
    float m0 = fmaxf(v[0], v[1]);
    float m1 = fmaxf(v[2], v[3]);
    float m2 = fmaxf(v[4], v[5]);
    float m3 = fmaxf(v[6], v[7]);
    float mx = fmaxf(fmaxf(m0, m1), fmaxf(fmaxf(m2, m3), v[8]));
    float s = __expf(v[0] - mx) + __expf(v[1] - mx) + __expf(v[2] - mx)
            + __expf(v[3] - mx) + __expf(v[4] - mx) + __expf(v[5] - mx)
            + __expf(v[6] - mx) + __expf(v[7] - mx) + __expf(v[8] - mx);
    return mx + __logf(s);
}

// ---------------- Kernel A: W12t[t][d] = sum_h W1[d][h]*W2[h][t]; b12 ----------------
// 1025 blocks (1 row each; block 1024 = bias path). Block 0 zeroes election counters.
__global__ __launch_bounds__(256) void k_w12(const float* __restrict__ W1,
                                             const float* __restrict__ b1,
                                             const float* __restrict__ W2,
                                             const float* __restrict__ b2,
                                             float* __restrict__ W12t,
                                             float* __restrict__ b12,
                                             unsigned int* __restrict__ cnt) {
    __shared__ float sh_w2[HD * TD];   // 36 KiB
    __shared__ float wred[4][TD];
    const int tid = threadIdx.x;
    const int wave = tid >> 6, lane = tid & 63;
    const int d = blockIdx.x;

    if (blockIdx.x == 0 && tid < 80) cnt[tid] = 0u;

    for (int i = tid; i < HD * TD / 4; i += 256)
        ((float4*)sh_w2)[i] = ((const float4*)W2)[i];
    __syncthreads();

    const float* row = (d < DD) ? (W1 + (size_t)d * HD) : b1;
    float4 x = ((const float4*)row)[tid];

    float acc[TD];
#pragma unroll
    for (int t = 0; t < TD; t++) acc[t] = 0.f;
#pragma unroll
    for (int u = 0; u < 4; u++) {
        float xv = (&x.x)[u];
        int h = tid * 4 + u;
#pragma unroll
        for (int t = 0; t < TD; t++) acc[t] += xv * sh_w2[h * TD + t];
    }
#pragma unroll
    for (int t = 0; t < TD; t++) {
        float v = acc[t];
#pragma unroll
        for (int m = 1; m < 64; m <<= 1) v += __shfl_xor(v, m);
        acc[t] = v;
    }
    if (lane == 0) {
#pragma unroll
        for (int t = 0; t < TD; t++) wred[wave][t] = acc[t];
    }
    __syncthreads();
    if (tid < TD) {
        float s = wred[0][tid] + wred[1][tid] + wred[2][tid] + wred[3][tid];
        if (d < DD) W12t[tid * DD + d] = s;
        else        b12[tid] = s + b2[tid];
    }
}

// ---------------- Kernel B: logits = X @ W12t^T + b12 ----------------
// 1024 blocks x 256 thr (4 blocks/CU, 16 waves/CU). 16-lane groups, 2 rows/group.
__global__ __launch_bounds__(256) void k_gemm2(const float* __restrict__ X,
                                               const float* __restrict__ W12t,
                                               const float* __restrict__ b12,
                                               float* __restrict__ logits) {
    __shared__ float wt[TD][DD];  // 36 KiB
    __shared__ float bb[TD];

    for (int i = threadIdx.x; i < TD * DD / 4; i += 256)
        ((float4*)&wt[0][0])[i] = ((const float4*)W12t)[i];
    if (threadIdx.x < TD) bb[threadIdx.x] = b12[threadIdx.x];
    __syncthreads();

    const int wave = threadIdx.x >> 6;
    const int lane = threadIdx.x & 63;
    const int g = lane >> 4;
    const int l16 = lane & 15;
    const int row0 = blockIdx.x * 32 + wave * 8 + g * 2;

    const float4* xr0 = (const float4*)(X + (size_t)row0 * DD);
    const float4* xr1 = xr0 + DD / 4;

    float acc0[TD], acc1[TD];
#pragma unroll
    for (int t = 0; t < TD; t++) { acc0[t] = 0.f; acc1[t] = 0.f; }

#pragma unroll 4
    for (int k = 0; k < 16; k++) {
        int d4 = l16 + k * 16;
        float4 x0 = xr0[d4];
        float4 x1 = xr1[d4];
#pragma unroll
        for (int t = 0; t < TD; t++) {
            const float4 w = *(const float4*)&wt[t][d4 * 4];
            acc0[t] += x0.x * w.x + x0.y * w.y + x0.z * w.z + x0.w * w.w;
            acc1[t] += x1.x * w.x + x1.y * w.y + x1.z * w.z + x1.w * w.w;
        }
    }

#pragma unroll
    for (int t = 0; t < TD; t++) {
        float v0 = acc0[t], v1 = acc1[t];
        v0 += __shfl_xor(v0, 1); v1 += __shfl_xor(v1, 1);
        v0 += __shfl_xor(v0, 2); v1 += __shfl_xor(v1, 2);
        v0 += __shfl_xor(v0, 4); v1 += __shfl_xor(v1, 4);
        v0 += __shfl_xor(v0, 8); v1 += __shfl_xor(v1, 8);
        acc0[t] = v0; acc1[t] = v1;
    }

    float* out0 = logits + (size_t)row0 * TD;
    float* out1 = out0 + TD;
    if (l16 < TD) {
        out0[l16] = acc0[l16] + bb[l16];
        out1[l16] = acc1[l16] + bb[l16];
    }
}

// ---------------- Kernel C: 32-leaf seg tree + elected fin + elected loss ----------------
// Grid 1024 = (b, s): b = blk>>4, s = blk&15. Element-per-thread throughout.
__global__ __launch_bounds__(256) void k_crf_all(const float* __restrict__ logits,
                                                 const int* __restrict__ labels,
                                                 const int* __restrict__ maskp,
                                                 const float* __restrict__ startp,
                                                 const float* __restrict__ endp,
                                                 const float* __restrict__ transp,
                                                 float* __restrict__ segP,
                                                 float* __restrict__ diff,
                                                 unsigned int* __restrict__ cnt,
                                                 float* __restrict__ out) {
    const int blk = blockIdx.x;
    const int b = blk >> 4, s = blk & 15;
    const int tid = threadIdx.x;

    __shared__ float tr[81];
    __shared__ float em[SEGL * 9];      // 288 floats, contiguous slice of logits
    __shared__ int   mk[SEGL];
    __shared__ float bufA[16 * 81];     // 1296
    __shared__ float bufB[8 * 81];      // 648
    __shared__ int   elect1, elect2;

    const int t0 = s * SEGL + 1;        // first step covered; leaf q -> t = t0+q

    {
        const float* src = logits + ((size_t)b * SD + t0) * TD;
        for (int i = tid; i < SEGL * 9; i += 256)
            em[i] = (t0 + i / 9 < SD) ? src[i] : 0.f;
    }
    if (tid < SEGL) {
        int t = t0 + tid;
        mk[tid] = (t < SD) ? maskp[b * SD + t] : 0;
    }
    if (tid < 81) tr[tid] = transp[tid];
    __syncthreads();

    // ---- level 1: 16 leaf-pair products, element-per-thread ----
    for (int e = tid; e < 16 * 81; e += 256) {
        int p = e / 81, r = e - p * 81;
        int i = r / 9, j = r - i * 9;
        int la = 2 * p, lb = 2 * p + 1;
        int mA = mk[la], mB = mk[lb];
        float o;
        if (mA && mB) {
            float v[9];
#pragma unroll
            for (int k = 0; k < 9; k++)
                v[k] = tr[i * 9 + k] + em[la * 9 + k] + tr[k * 9 + j];
            o = lse9(v) + em[lb * 9 + j];
        } else if (mA) {
            o = tr[r] + em[la * 9 + j];
        } else if (mB) {
            o = tr[r] + em[lb * 9 + j];
        } else {
            o = (i == j) ? 0.f : NEGI;
        }
        bufA[e] = o;
    }
    __syncthreads();

#define COMBINE(SRC, DST, NP)                                        \
    for (int e = tid; e < (NP) * 81; e += 256) {                     \
        int p = e / 81, r = e - p * 81;                              \
        int i = r / 9, j = r - i * 9;                                \
        const float* Am = (SRC) + (2 * p) * 81;                      \
        const float* Bm = Am + 81;                                   \
        float v[9];                                                  \
        _Pragma("unroll")                                            \
        for (int k = 0; k < 9; k++) v[k] = Am[i * 9 + k] + Bm[k * 9 + j]; \
        (DST)[e] = lse9(v);                                          \
    }                                                                \
    __syncthreads();

    COMBINE(bufA, bufB, 8)    // 16 -> 8
    COMBINE(bufB, bufA, 4)    // 8  -> 4
    COMBINE(bufA, bufB, 2)    // 4  -> 2

    if (tid < 81) {           // 2 -> 1, straight to global
        int i = tid / 9, j = tid - (tid / 9) * 9;
        float v[9];
#pragma unroll
        for (int k = 0; k < 9; k++) v[k] = bufB[i * 9 + k] + bufB[81 + k * 9 + j];
        segP[(size_t)blk * 81 + tid] = lse9(v);
    }
    __syncthreads();

    // ---- election: 16th seg block of batch b runs the fin ----
    if (tid == 0) {
        __threadfence();
        unsigned int old = __hip_atomic_fetch_add(&cnt[b], 1u, __ATOMIC_ACQ_REL,
                                                  __HIP_MEMORY_SCOPE_AGENT);
        elect1 = (old == NSEG - 1);
    }
    __syncthreads();
    if (!elect1) return;

    // ---- fin: combine 16 segment matrices ----
    for (int i = tid; i < 16 * 81; i += 256)
        bufA[i] = __hip_atomic_load(&segP[(size_t)b * NSEG * 81 + i], __ATOMIC_RELAXED,
                                    __HIP_MEMORY_SCOPE_AGENT);
    __syncthreads();

    COMBINE(bufA, bufB, 8)    // 16 -> 8
    COMBINE(bufB, bufA, 4)    // 8  -> 4
    COMBINE(bufA, bufB, 2)    // 4  -> 2

    float* P    = bufA + 648;   // 81
    float* finv = bufA + 736;   // 81
    if (tid < 81) {
        int i = tid / 9, j = tid - (tid / 9) * 9;
        float v[9];
#pragma unroll
        for (int k = 0; k < 9; k++) v[k] = bufB[i * 9 + k] + bufB[81 + k * 9 + j];
        P[tid] = lse9(v);
    }
    __syncthreads();

    if (tid < 81) {
        int k = tid / 9, j = tid - (tid / 9) * 9;
        finv[tid] = startp[k] + logits[(size_t)b * SD * TD + k] + P[tid] + endp[j];
    }

    float* red = bufA + 900;           // 256 floats (900..1155 < 1296)
    int*  redi = (int*)bufB;           // 256 ints, bufB dead
    float part = 0.f;
    for (int t = 1 + tid; t < SD; t += 256) {
        if (maskp[b * SD + t]) {
            int tgp = labels[b * SD + t - 1];
            int tgc = labels[b * SD + t];
            part += transp[tgp * TD + tgc] + logits[((size_t)b * SD + t) * TD + tgc];
        }
    }
    int lastt = 0;
    for (int t = tid; t < SD; t += 256) {
        if (maskp[b * SD + t]) lastt = max(lastt, t);
    }
    red[tid] = part;
    redi[tid] = lastt;
    __syncthreads();

    if (tid < 64) {
        float p4 = red[tid] + red[tid + 64] + red[tid + 128] + red[tid + 192];
        int l4 = max(max(redi[tid], redi[tid + 64]), max(redi[tid + 128], redi[tid + 192]));
#pragma unroll
        for (int m = 1; m < 64; m <<= 1) {
            p4 += __shfl_xor(p4, m);
            l4 = max(l4, __shfl_xor(l4, m));
        }
        float v1 = finv[tid];
        float v2 = (tid + 64 < 81) ? finv[tid + 64] : NEGI;
        float mx = fmaxf(v1, v2);
#pragma unroll
        for (int m = 1; m < 64; m <<= 1) mx = fmaxf(mx, __shfl_xor(mx, m));
        float ssum = __expf(v1 - mx) + __expf(v2 - mx);
#pragma unroll
        for (int m = 1; m < 64; m <<= 1) ssum += __shfl_xor(ssum, m);
        float logz = mx + __logf(ssum);

        if (tid == 0) {
            int tg0 = labels[b * SD];
            int tgl = labels[b * SD + l4];
            float score = p4 + startp[tg0] + logits[(size_t)b * SD * TD + tg0] + endp[tgl];
            diff[b] = score - logz;
        }
    }
    __syncthreads();

    // ---- election: 64th fin runs the loss ----
    if (tid == 0) {
        __threadfence();
        unsigned int old = __hip_atomic_fetch_add(&cnt[64], 1u, __ATOMIC_ACQ_REL,
                                                  __HIP_MEMORY_SCOPE_AGENT);
        elect2 = (old == BD - 1);
    }
    __syncthreads();
    if (!elect2) return;

    if (tid < 64) {
        float v = __hip_atomic_load(&diff[tid], __ATOMIC_RELAXED,
                                    __HIP_MEMORY_SCOPE_AGENT);
#pragma unroll
        for (int m = 1; m < 64; m <<= 1) v += __shfl_xor(v, m);
        if (tid == 0) out[0] = -v / (float)BD;
    }
}

extern "C" void kernel_launch(void* const* d_in, const int* in_sizes, int n_in,
                              void* d_out, int out_size, void* d_ws, size_t ws_size,
                              hipStream_t stream) {
    const float* X      = (const float*)d_in[0];
    const int*   labels = (const int*)d_in[1];
    const int*   maskp  = (const int*)d_in[2];
    const float* W1     = (const float*)d_in[3];
    const float* b1     = (const float*)d_in[4];
    const float* W2     = (const float*)d_in[5];
    const float* b2     = (const float*)d_in[6];
    const float* startp = (const float*)d_in[7];
    const float* endp   = (const float*)d_in[8];
    const float* transp = (const float*)d_in[9];

    float* out = (float*)d_out;
    float* ws = (float*)d_ws;

    float* diff = ws;                         // 64 floats
    float* W12t = ws + 64;                    // 9216
    float* b12  = ws + 64 + DD * TD;          // 9 (+pad to 16)
    float* segP = ws + 64 + DD * TD + 16;     // 64*16*81 = 82944 floats
    unsigned int* cnt = (unsigned int*)(ws + 64 + DD * TD + 16 + BD * NSEG * 81);  // 80 u32
    float* logits = out + 1;                  // [B,S,T] fp32

    hipLaunchKernelGGL(k_w12, dim3(DD + 1), dim3(256), 0, stream,
                       W1, b1, W2, b2, W12t, b12, cnt);
    hipLaunchKernelGGL(k_gemm2, dim3(BD * SD / 32), dim3(256), 0, stream,
                       X, W12t, b12, logits);
    hipLaunchKernelGGL(k_crf_all, dim3(BD * NSEG), dim3(256), 0, stream,
                       logits, labels, maskp, startp, endp, transp, segP, diff, cnt, out);
}

// Round 8
// 60.021 us; speedup vs baseline: 1.6129x; 1.6129x over previous
//
#include <hip/hip_runtime.h>

#define BD 64
#define SD 512
#define DD 1024
#define HD 1024
#define TD 9
#define NSEG 16
#define SEGL 32
#define NEGI -1e30f

__device__ __forceinline__ float lse9(const float v[9]) {
    float m0 = fmaxf(v[0], v[1]);
    float m1 = fmaxf(v[2], v[3]);
    float m2 = fmaxf(v[4], v[5]);
    float m3 = fmaxf(v[6], v[7]);
    float mx = fmaxf(fmaxf(m0, m1), fmaxf(fmaxf(m2, m3), v[8]));
    float s = __expf(v[0] - mx) + __expf(v[1] - mx) + __expf(v[2] - mx)
            + __expf(v[3] - mx) + __expf(v[4] - mx) + __expf(v[5] - mx)
            + __expf(v[6] - mx) + __expf(v[7] - mx) + __expf(v[8] - mx);
    return mx + __logf(s);
}

// ---------------- Kernel A: W12t[t][d] = sum_h W1[d][h]*W2[h][t]; b12 ----------------
// 1025 blocks (1 row each; block 1024 = bias path), shfl-tree reduction.
__global__ __launch_bounds__(256) void k_w12(const float* __restrict__ W1,
                                             const float* __restrict__ b1,
                                             const float* __restrict__ W2,
                                             const float* __restrict__ b2,
                                             float* __restrict__ W12t,
                                             float* __restrict__ b12) {
    __shared__ float sh_w2[HD * TD];   // 36 KiB
    __shared__ float wred[4][TD];
    const int tid = threadIdx.x;
    const int wave = tid >> 6, lane = tid & 63;
    const int d = blockIdx.x;

    for (int i = tid; i < HD * TD / 4; i += 256)
        ((float4*)sh_w2)[i] = ((const float4*)W2)[i];
    __syncthreads();

    const float* row = (d < DD) ? (W1 + (size_t)d * HD) : b1;
    float4 x = ((const float4*)row)[tid];

    float acc[TD];
#pragma unroll
    for (int t = 0; t < TD; t++) acc[t] = 0.f;
#pragma unroll
    for (int u = 0; u < 4; u++) {
        float xv = (&x.x)[u];
        int h = tid * 4 + u;
#pragma unroll
        for (int t = 0; t < TD; t++) acc[t] += xv * sh_w2[h * TD + t];
    }
#pragma unroll
    for (int t = 0; t < TD; t++) {
        float v = acc[t];
#pragma unroll
        for (int m = 1; m < 64; m <<= 1) v += __shfl_xor(v, m);
        acc[t] = v;
    }
    if (lane == 0) {
#pragma unroll
        for (int t = 0; t < TD; t++) wred[wave][t] = acc[t];
    }
    __syncthreads();
    if (tid < TD) {
        float s = wred[0][tid] + wred[1][tid] + wred[2][tid] + wred[3][tid];
        if (d < DD) W12t[tid * DD + d] = s;
        else        b12[tid] = s + b2[tid];
    }
}

// ---------------- Kernel B: logits = X @ W12t^T + b12 ----------------
// 1024 blocks x 256 thr (4 blocks/CU, 16 waves/CU). 16-lane groups, 2 rows/group.
__global__ __launch_bounds__(256) void k_gemm2(const float* __restrict__ X,
                                               const float* __restrict__ W12t,
                                               const float* __restrict__ b12,
                                               float* __restrict__ logits) {
    __shared__ float wt[TD][DD];  // 36 KiB
    __shared__ float bb[TD];

    for (int i = threadIdx.x; i < TD * DD / 4; i += 256)
        ((float4*)&wt[0][0])[i] = ((const float4*)W12t)[i];
    if (threadIdx.x < TD) bb[threadIdx.x] = b12[threadIdx.x];
    __syncthreads();

    const int wave = threadIdx.x >> 6;
    const int lane = threadIdx.x & 63;
    const int g = lane >> 4;
    const int l16 = lane & 15;
    const int row0 = blockIdx.x * 32 + wave * 8 + g * 2;

    const float4* xr0 = (const float4*)(X + (size_t)row0 * DD);
    const float4* xr1 = xr0 + DD / 4;

    float acc0[TD], acc1[TD];
#pragma unroll
    for (int t = 0; t < TD; t++) { acc0[t] = 0.f; acc1[t] = 0.f; }

#pragma unroll 4
    for (int k = 0; k < 16; k++) {
        int d4 = l16 + k * 16;
        float4 x0 = xr0[d4];
        float4 x1 = xr1[d4];
#pragma unroll
        for (int t = 0; t < TD; t++) {
            const float4 w = *(const float4*)&wt[t][d4 * 4];
            acc0[t] += x0.x * w.x + x0.y * w.y + x0.z * w.z + x0.w * w.w;
            acc1[t] += x1.x * w.x + x1.y * w.y + x1.z * w.z + x1.w * w.w;
        }
    }

#pragma unroll
    for (int t = 0; t < TD; t++) {
        float v0 = acc0[t], v1 = acc1[t];
        v0 += __shfl_xor(v0, 1); v1 += __shfl_xor(v1, 1);
        v0 += __shfl_xor(v0, 2); v1 += __shfl_xor(v1, 2);
        v0 += __shfl_xor(v0, 4); v1 += __shfl_xor(v1, 4);
        v0 += __shfl_xor(v0, 8); v1 += __shfl_xor(v1, 8);
        acc0[t] = v0; acc1[t] = v1;
    }

    float* out0 = logits + (size_t)row0 * TD;
    float* out1 = out0 + TD;
    if (l16 < TD) {
        out0[l16] = acc0[l16] + bb[l16];
        out1[l16] = acc1[l16] + bb[l16];
    }
}

// ---------------- Kernel C1: 32-leaf per-segment semiring tree ----------------
// Grid 1024 = (b, s): b = blk>>4, s = blk&15. Element-per-thread throughout.
__global__ __launch_bounds__(256) void k_crf_seg(const float* __restrict__ logits,
                                                 const int* __restrict__ maskp,
                                                 const float* __restrict__ transp,
                                                 float* __restrict__ segP) {
    const int blk = blockIdx.x;
    const int b = blk >> 4, s = blk & 15;
    const int tid = threadIdx.x;

    __shared__ float tr[81];
    __shared__ float em[SEGL * 9];      // 288 floats, contiguous slice of logits
    __shared__ int   mk[SEGL];
    __shared__ float bufA[16 * 81];     // 1296
    __shared__ float bufB[8 * 81];      // 648

    const int t0 = s * SEGL + 1;        // leaf q -> step t = t0+q

    {
        const float* src = logits + ((size_t)b * SD + t0) * TD;
        for (int i = tid; i < SEGL * 9; i += 256)
            em[i] = (t0 + i / 9 < SD) ? src[i] : 0.f;
    }
    if (tid < SEGL) {
        int t = t0 + tid;
        mk[tid] = (t < SD) ? maskp[b * SD + t] : 0;
    }
    if (tid < 81) tr[tid] = transp[tid];
    __syncthreads();

    // ---- level 1: 16 leaf-pair products, element-per-thread ----
    for (int e = tid; e < 16 * 81; e += 256) {
        int p = e / 81, r = e - p * 81;
        int i = r / 9, j = r - i * 9;
        int la = 2 * p, lb = 2 * p + 1;
        int mA = mk[la], mB = mk[lb];
        float o;
        if (mA && mB) {
            float v[9];
#pragma unroll
            for (int k = 0; k < 9; k++)
                v[k] = tr[i * 9 + k] + em[la * 9 + k] + tr[k * 9 + j];
            o = lse9(v) + em[lb * 9 + j];
        } else if (mA) {
            o = tr[r] + em[la * 9 + j];
        } else if (mB) {
            o = tr[r] + em[lb * 9 + j];
        } else {
            o = (i == j) ? 0.f : NEGI;
        }
        bufA[e] = o;
    }
    __syncthreads();

#define COMBINE(SRC, DST, NP)                                        \
    for (int e = tid; e < (NP) * 81; e += 256) {                     \
        int p = e / 81, r = e - p * 81;                              \
        int i = r / 9, j = r - i * 9;                                \
        const float* Am = (SRC) + (2 * p) * 81;                      \
        const float* Bm = Am + 81;                                   \
        float v[9];                                                  \
        _Pragma("unroll")                                            \
        for (int k = 0; k < 9; k++) v[k] = Am[i * 9 + k] + Bm[k * 9 + j]; \
        (DST)[e] = lse9(v);                                          \
    }                                                                \
    __syncthreads();

    COMBINE(bufA, bufB, 8)    // 16 -> 8
    COMBINE(bufB, bufA, 4)    // 8  -> 4
    COMBINE(bufA, bufB, 2)    // 4  -> 2

    if (tid < 81) {           // 2 -> 1, straight to global
        int i = tid / 9, j = tid - (tid / 9) * 9;
        float v[9];
#pragma unroll
        for (int k = 0; k < 9; k++) v[k] = bufB[i * 9 + k] + bufB[81 + k * 9 + j];
        segP[(size_t)blk * 81 + tid] = lse9(v);
    }
}

// ---------------- Kernel C2: combine 16 segment matrices, log_z, numerator ----------------
__global__ __launch_bounds__(256) void k_crf_fin(const float* __restrict__ logits,
                                                 const int* __restrict__ labels,
                                                 const int* __restrict__ maskp,
                                                 const float* __restrict__ startp,
                                                 const float* __restrict__ endp,
                                                 const float* __restrict__ transp,
                                                 const float* __restrict__ segP,
                                                 float* __restrict__ diff) {
    const int b = blockIdx.x;
    const int tid = threadIdx.x;

    __shared__ float S[16 * 81];
    __shared__ float A8[8 * 81];
    __shared__ float A4[4 * 81];
    __shared__ float A2[2 * 81];
    __shared__ float P[81];
    __shared__ float finv[81];
    __shared__ float red[256];
    __shared__ int   redi[256];

    for (int i = tid; i < 16 * 81; i += 256) S[i] = segP[(size_t)b * NSEG * 81 + i];
    __syncthreads();

    COMBINE(S, A8, 8)     // 16 -> 8
    COMBINE(A8, A4, 4)    // 8  -> 4
    COMBINE(A4, A2, 2)    // 4  -> 2

    if (tid < 81) {
        int i = tid / 9, j = tid - (tid / 9) * 9;
        float v[9];
#pragma unroll
        for (int k = 0; k < 9; k++) v[k] = A2[i * 9 + k] + A2[81 + k * 9 + j];
        P[tid] = lse9(v);
    }
    __syncthreads();

    if (tid < 81) {
        int k = tid / 9, j = tid - (tid / 9) * 9;
        finv[tid] = startp[k] + logits[(size_t)b * SD * TD + k] + P[tid] + endp[j];
    }

    float part = 0.f;
    for (int t = 1 + tid; t < SD; t += 256) {
        if (maskp[b * SD + t]) {
            int tgp = labels[b * SD + t - 1];
            int tgc = labels[b * SD + t];
            part += transp[tgp * TD + tgc] + logits[((size_t)b * SD + t) * TD + tgc];
        }
    }
    int lastt = 0;
    for (int t = tid; t < SD; t += 256) {
        if (maskp[b * SD + t]) lastt = max(lastt, t);
    }
    red[tid] = part;
    redi[tid] = lastt;
    __syncthreads();

    if (tid < 64) {
        float p4 = red[tid] + red[tid + 64] + red[tid + 128] + red[tid + 192];
        int l4 = max(max(redi[tid], redi[tid + 64]), max(redi[tid + 128], redi[tid + 192]));
#pragma unroll
        for (int m = 1; m < 64; m <<= 1) {
            p4 += __shfl_xor(p4, m);
            l4 = max(l4, __shfl_xor(l4, m));
        }
        float v1 = finv[tid];
        float v2 = (tid + 64 < 81) ? finv[tid + 64] : NEGI;
        float mx = fmaxf(v1, v2);
#pragma unroll
        for (int m = 1; m < 64; m <<= 1) mx = fmaxf(mx, __shfl_xor(mx, m));
        float ssum = __expf(v1 - mx) + __expf(v2 - mx);
#pragma unroll
        for (int m = 1; m < 64; m <<= 1) ssum += __shfl_xor(ssum, m);
        float logz = mx + __logf(ssum);

        if (tid == 0) {
            int tg0 = labels[b * SD];
            int tgl = labels[b * SD + l4];
            float score = p4 + startp[tg0] + logits[(size_t)b * SD * TD + tg0] + endp[tgl];
            diff[b] = score - logz;
        }
    }
}

// ---------------- Kernel D: loss = -mean(diff) ----------------
__global__ __launch_bounds__(64) void k_loss(const float* __restrict__ diff,
                                             float* __restrict__ out) {
    float v = (threadIdx.x < BD) ? diff[threadIdx.x] : 0.f;
#pragma unroll
    for (int m = 1; m < 64; m <<= 1) v += __shfl_xor(v, m);
    if (threadIdx.x == 0) out[0] = -v / (float)BD;
}

extern "C" void kernel_launch(void* const* d_in, const int* in_sizes, int n_in,
                              void* d_out, int out_size, void* d_ws, size_t ws_size,
                              hipStream_t stream) {
    const float* X      = (const float*)d_in[0];
    const int*   labels = (const int*)d_in[1];
    const int*   maskp  = (const int*)d_in[2];
    const float* W1     = (const float*)d_in[3];
    const float* b1     = (const float*)d_in[4];
    const float* W2     = (const float*)d_in[5];
    const float* b2     = (const float*)d_in[6];
    const float* startp = (const float*)d_in[7];
    const float* endp   = (const float*)d_in[8];
    const float* transp = (const float*)d_in[9];

    float* out = (float*)d_out;
    float* ws = (float*)d_ws;

    float* diff = ws;                       // 64
    float* W12t = ws + 64;                  // 9216
    float* b12  = ws + 64 + DD * TD;        // 9 (+pad)
    float* segP = ws + 64 + DD * TD + 16;   // 64*16*81 floats
    float* logits = out + 1;                // [B,S,T] fp32

    hipLaunchKernelGGL(k_w12, dim3(DD + 1), dim3(256), 0, stream,
                       W1, b1, W2, b2, W12t, b12);
    hipLaunchKernelGGL(k_gemm2, dim3(BD * SD / 32), dim3(256), 0, stream,
                       X, W12t, b12, logits);
    hipLaunchKernelGGL(k_crf_seg, dim3(BD * NSEG), dim3(256), 0, stream,
                       logits, maskp, transp, segP);
    hipLaunchKernelGGL(k_crf_fin, dim3(BD), dim3(256), 0, stream,
                       logits, labels, maskp, startp, endp, transp, segP, diff);
    hipLaunchKernelGGL(k_loss, dim3(1), dim3(64), 0, stream, diff, out);
}